// Round 10
// baseline (39.783 us; speedup 1.0000x reference)
//
#include <hip/hip_runtime.h>

// GaussianAntecedent: out[n,r] = mem[n,r] / (sum_r mem[n,r] + 1e-8)
// mem = exp2( sum_d max( -(q*x + pn)^2 , L ) ),
//   q = sqrt(0.5*log2 e)/(sigma+eps), pn = -c*q, L = log2(1e-8) < 0
//
// R9 post-mortem: the scalar-load X transport is the bottleneck --
// 12.8MB streams through the tiny K$, each pair-iteration stalls on an
// L2/HBM-latency s_waitcnt that depth-1 prefetch can't hide (3 rounds of
// tuning all land 35-58us). R10: X goes through the VECTOR path:
// each wave stages its own 8 rows with ONE coalesced float4 load
// (64 lanes x 16B = 1KB = 8 rows) + ds_write_b128 into linear LDS,
// then computes from uniform-address ds_read_b128 (broadcast, ~60cy,
// conflict-free). One vmcnt wait per 8 rows, issued at wave start so it
// hides under the constant-table gather. Same-wave LDS exchange needs no
// barrier. Kept: q/pn table precompute (no divides), VGPR pin, packed
// pair math, DPP wave reduce, coalesced stores. 100000 = 3125 x 32 exact.

typedef float v2f __attribute__((ext_vector_type(2)));

constexpr int DDIM = 32;
constexpr int RR   = 64;
constexpr int RPW  = 8;          // rows per wave -> 12500 waves
constexpr int WPB  = 4;          // waves per block
constexpr int RPB  = RPW * WPB;  // 32 rows per block

__device__ inline float fast_exp2(float x) {
#if __has_builtin(__builtin_amdgcn_exp2f)
    return __builtin_amdgcn_exp2f(x);
#else
    return exp2f(x);
#endif
}

template <int CTRL>
__device__ inline float dpp_add(float x) {
    int t = __builtin_amdgcn_update_dpp(0, __float_as_int(x), CTRL, 0xF, 0xF, true);
    return x + __int_as_float(t);
}

// Wave64 sum, result broadcast to all lanes via SGPR.
__device__ inline float wave_sum_bcast(float x) {
    x = dpp_add<0x111>(x);  // row_shr:1
    x = dpp_add<0x112>(x);  // row_shr:2
    x = dpp_add<0x114>(x);  // row_shr:4
    x = dpp_add<0x118>(x);  // row_shr:8
    x = dpp_add<0x142>(x);  // row_bcast:15
    x = dpp_add<0x143>(x);  // row_bcast:31
    return __int_as_float(__builtin_amdgcn_readlane(__float_as_int(x), 63));
}

// ---- setup: q/pn tables, run once per launch (deterministic) ----
__global__ void gauss_setup_kernel(const float* __restrict__ centers,
                                   const float* __restrict__ sigma,
                                   float* __restrict__ ws) {
    const float SQK = 0.84932180028801907f;   // sqrt(0.5 * log2(e))
    int idx = blockIdx.x * blockDim.x + threadIdx.x;
    if (idx < RR * DDIM) {
        float q = SQK / (sigma[idx] + 1e-8f);
        ws[idx] = q;
        ws[RR * DDIM + idx] = -centers[idx] * q;
    }
}

__global__ __launch_bounds__(256, 4) void gauss_antecedent_kernel(
    const float* __restrict__ X,
    const float* __restrict__ qtab,   // d_ws: [RR*DDIM] q then [RR*DDIM] pn
    float* __restrict__ out, int N)
{
    __shared__ float xs[RPB * DDIM];  // 4 KB, linear, 1KB per wave
    const int lane = threadIdx.x & 63;
    const int wv   = threadIdx.x >> 6;
    const int row0 = blockIdx.x * RPB + wv * RPW;   // this wave's first row

    const float LC = -26.575424759098897f;    // log2(1e-8)
    const v2f L2 = {LC, LC};

    float* myxs = &xs[wv * RPW * DDIM];
    const bool full = (row0 + RPW <= N);

    // ---- stage this wave's 8 rows: ONE coalesced float4 vector load ----
    // lane l carries row (l/8), dims (l%8)*4..+3 ; 64 x 16B = 1KB = 8 rows.
    // Issued first so its latency hides under the table gather below.
    float4 xv;
    if (full) {
        xv = *reinterpret_cast<const float4*>(X + (size_t)row0 * DDIM + lane * 4);
    }

    // ---- per-lane (rule = lane) constants: plain loads, no divides ----
    const float4* __restrict__ qv =
        reinterpret_cast<const float4*>(qtab + lane * DDIM);
    const float4* __restrict__ pv =
        reinterpret_cast<const float4*>(qtab + RR * DDIM + lane * DDIM);
    v2f q2[DDIM / 2], pn2[DDIM / 2];
    #pragma unroll
    for (int j = 0; j < 8; ++j) {
        float4 a = qv[j], b = pv[j];
        q2[2 * j]      = (v2f){a.x, a.y};
        q2[2 * j + 1]  = (v2f){a.z, a.w};
        pn2[2 * j]     = (v2f){b.x, b.y};
        pn2[2 * j + 1] = (v2f){b.z, b.w};
    }
    // Pin constants in VGPRs (opaque asm: cannot be rematerialized/reloaded).
    #pragma unroll
    for (int j = 0; j < DDIM / 2; ++j) {
        asm volatile("" : "+v"(q2[j]), "+v"(pn2[j]));
    }

    if (full) {
        // LDS write of the staged rows; same-wave lockstep -> no barrier.
        *reinterpret_cast<float4*>(&myxs[lane * 4]) = xv;

        #pragma unroll
        for (int p = 0; p < RPW / 2; ++p) {
            // rows 2p, 2p+1 read via uniform-address ds_read_b128 (broadcast)
            const float4* __restrict__ ra =
                reinterpret_cast<const float4*>(&myxs[(2 * p) * DDIM]);
            const float4* __restrict__ rb =
                reinterpret_cast<const float4*>(&myxs[(2 * p + 1) * DDIM]);

            v2f Ba[2] = {{0.f, 0.f}, {0.f, 0.f}};
            v2f Bb[2] = {{0.f, 0.f}, {0.f, 0.f}};
            #pragma unroll
            for (int j = 0; j < 8; ++j) {
                float4 a = ra[j], b = rb[j];
                v2f a0 = {a.x, a.y}, a1 = {a.z, a.w};
                v2f b0 = {b.x, b.y}, b1 = {b.z, b.w};
                v2f ta0 = __builtin_elementwise_fma(q2[2*j],   a0, pn2[2*j]);
                v2f ta1 = __builtin_elementwise_fma(q2[2*j+1], a1, pn2[2*j+1]);
                v2f tb0 = __builtin_elementwise_fma(q2[2*j],   b0, pn2[2*j]);
                v2f tb1 = __builtin_elementwise_fma(q2[2*j+1], b1, pn2[2*j+1]);
                // B = max(B - t*t, B + L)  (exact: B + max(-t^2, L))
                v2f ua0 = __builtin_elementwise_fma(ta0, -ta0, Ba[0]);
                v2f ua1 = __builtin_elementwise_fma(ta1, -ta1, Ba[1]);
                v2f ub0 = __builtin_elementwise_fma(tb0, -tb0, Bb[0]);
                v2f ub1 = __builtin_elementwise_fma(tb1, -tb1, Bb[1]);
                Ba[0] = __builtin_elementwise_max(ua0, Ba[0] + L2);
                Ba[1] = __builtin_elementwise_max(ua1, Ba[1] + L2);
                Bb[0] = __builtin_elementwise_max(ub0, Bb[0] + L2);
                Bb[1] = __builtin_elementwise_max(ub1, Bb[1] + L2);
            }

            v2f sa = Ba[0] + Ba[1];
            v2f sb = Bb[0] + Bb[1];
            float ma = fast_exp2(sa.x + sa.y);
            float mb = fast_exp2(sb.x + sb.y);
            float Sa = wave_sum_bcast(ma);
            float Sb = wave_sum_bcast(mb);
            const size_t o = (size_t)(row0 + 2 * p) * RR + lane;
            out[o]      = ma * __builtin_amdgcn_rcpf(Sa + 1e-8f);
            out[o + RR] = mb * __builtin_amdgcn_rcpf(Sb + 1e-8f);
        }
    } else if (row0 < N) {
        // ---- tail path (not taken for N=100000): direct global row reads ----
        for (int n = row0; n < N; ++n) {
            const int ns = __builtin_amdgcn_readfirstlane(n);
            const float4* __restrict__ xr =
                reinterpret_cast<const float4*>(X + (size_t)ns * DDIM);
            v2f B[2] = {{0.f, 0.f}, {0.f, 0.f}};
            #pragma unroll
            for (int j = 0; j < 8; ++j) {
                float4 xj = xr[j];
                v2f a0 = {xj.x, xj.y}, a1 = {xj.z, xj.w};
                v2f t0 = __builtin_elementwise_fma(q2[2*j],   a0, pn2[2*j]);
                v2f t1 = __builtin_elementwise_fma(q2[2*j+1], a1, pn2[2*j+1]);
                v2f u0 = __builtin_elementwise_fma(t0, -t0, B[0]);
                v2f u1 = __builtin_elementwise_fma(t1, -t1, B[1]);
                B[0] = __builtin_elementwise_max(u0, B[0] + L2);
                B[1] = __builtin_elementwise_max(u1, B[1] + L2);
            }
            v2f s = B[0] + B[1];
            float mem = fast_exp2(s.x + s.y);
            float S = wave_sum_bcast(mem);
            out[(size_t)ns * RR + lane] = mem * __builtin_amdgcn_rcpf(S + 1e-8f);
        }
    }
}

extern "C" void kernel_launch(void* const* d_in, const int* in_sizes, int n_in,
                              void* d_out, int out_size, void* d_ws, size_t ws_size,
                              hipStream_t stream) {
    const float* X       = (const float*)d_in[0];
    const float* centers = (const float*)d_in[1];
    const float* sigma   = (const float*)d_in[2];
    float* out = (float*)d_out;
    float* ws  = (float*)d_ws;   // needs 2*64*32*4 = 16 KB

    const int N = in_sizes[0] / DDIM;  // 100000

    // 1) build q/pn tables (2048 elems)
    gauss_setup_kernel<<<(RR * DDIM + 255) / 256, 256, 0, stream>>>(
        centers, sigma, ws);

    // 2) main kernel: 3125 blocks x 256 threads (N = 3125 * 32 exactly)
    const int grid = (N + RPB - 1) / RPB;
    gauss_antecedent_kernel<<<grid, 256, 0, stream>>>(X, ws, out, N);
}